// Round 6
// baseline (14023.296 us; speedup 1.0000x reference)
//
#include <hip/hip_runtime.h>
#include <hip/hip_bf16.h>

typedef __attribute__((ext_vector_type(8))) _Float16 half8;
typedef __attribute__((ext_vector_type(4))) float floatx4;

#define NTS 512    // timesteps
#define NB  64     // batch
#define NI  256    // input dim
#define NH  512    // hidden
#define NWG 256
#define NTHR 128

#define LOSCALE 4096.0f
#define LOINV   (1.0f / 4096.0f)

// fp32 -> (hi f16, lo f16 scaled by 2^12)  — lo stays f16-normal (no flush)
static __device__ __forceinline__ void split8s(const float* p, half8& hi, half8& lo) {
  float4 a = *(const float4*)p;
  float4 b = *(const float4*)(p + 4);
  float v[8] = {a.x, a.y, a.z, a.w, b.x, b.y, b.z, b.w};
#pragma unroll
  for (int i = 0; i < 8; ++i) {
    _Float16 h = (_Float16)v[i];
    hi[i] = h;
    lo[i] = (_Float16)((v[i] - (float)h) * LOSCALE);
  }
}

// pack one h cell: low16 = hi(f16), high16 = lo(f16, scaled 2^12)
static __device__ __forceinline__ unsigned pack_cell(float v) {
  _Float16 h = (_Float16)v;
  _Float16 l = (_Float16)((v - (float)h) * LOSCALE);
  union { _Float16 f; unsigned short s; } uh, ul;
  uh.f = h; ul.f = l;
  return ((unsigned)ul.s << 16) | (unsigned)uh.s;
}

// 8 packed cells via 4 agent-scope u64 atomic loads (cache-coherent), deinterleave
static __device__ __forceinline__ void load_cells(const unsigned* p, half8& ah, half8& al) {
  union { unsigned u[4]; half8 h; } A, L;
#pragma unroll
  for (int q = 0; q < 4; ++q) {
    unsigned long long Q = __hip_atomic_load((const unsigned long long*)(p + 2 * q),
                                             __ATOMIC_RELAXED, __HIP_MEMORY_SCOPE_AGENT);
    unsigned c0 = (unsigned)Q, c1 = (unsigned)(Q >> 32);
    A.u[q] = (c0 & 0xFFFFu) | (c1 << 16);
    L.u[q] = (c0 >> 16)     | (c1 & 0xFFFF0000u);
  }
  ah = A.h; al = L.h;
}

// Persistent LSTM, FP32 OUTPUT (reference dtype). Self-calibrating MFMA C-layout.
// 256 wgs; wg (mh,ng) owns batch rows [16mh,16mh+16) x 8 hidden cols [8ng,8ng+8).
__global__ void __launch_bounds__(NTHR, 1) lstm_persist_v6(
    const float* __restrict__ x,     // [512][64][256] fp32
    const float* __restrict__ h0,    // [64][512] fp32
    const float* __restrict__ c0,    // [64][512] fp32
    const float* __restrict__ w_ih,  // [2048][256] fp32
    const float* __restrict__ w_hh,  // [2048][512] fp32
    const float* __restrict__ b_ih,  // [2048] fp32
    const float* __restrict__ b_hh,  // [2048] fp32
    float* __restrict__ out,         // [512][64][512] ++ h_f ++ c_f (FP32)
    unsigned* __restrict__ hbuf,     // [2][64][512] packed u32 cells
    int* __restrict__ flags)         // [256] = [mh][ng], pre-zeroed
{
  const int wg   = blockIdx.x;
  const int mh   = wg & 3;        // batch quarter (group)
  const int ng   = wg >> 2;       // hidden-col group (8 cols)
  const int b0   = mh * 16;
  const int j0   = ng * 8;
  const int tid  = threadIdx.x;
  const int wv   = tid >> 6;      // 0: gates i,f   1: gates g,o
  const int lane = tid & 63;
  const int ln   = lane & 15;

  __shared__ float gates[16][33];  // [batch_local][gate_col_in_wg], padded

  // ---- EMPIRICAL layout probes: decode (local_row, local_col) of each acc slot ----
  int row_l[4], col_l[4];
  {
    half8 ones, rowv;
#pragma unroll
    for (int i = 0; i < 8; ++i) { ones[i] = (_Float16)1.0f; rowv[i] = (_Float16)(float)ln; }
    floatx4 z = {0.f, 0.f, 0.f, 0.f};
    floatx4 p1 = __builtin_amdgcn_mfma_f32_16x16x32_f16(rowv, ones, z, 0, 0, 0);
    floatx4 p2 = __builtin_amdgcn_mfma_f32_16x16x32_f16(ones, rowv, z, 0, 0, 0);
#pragma unroll
    for (int r = 0; r < 4; ++r) {
      row_l[r] = (int)(p1[r] * (1.0f / 32.0f) + 0.5f);
      col_l[r] = (int)(p2[r] * (1.0f / 32.0f) + 0.5f);
    }
  }

  // ---- B fragments (weights): fp32 -> scaled-split f16, pinned in registers ----
  half8 whh_hi[16], whh_lo[16], wih_hi[8], wih_lo[8];
  {
    const int gate2 = wv * 2 + (ln >> 3);            // 0..3 = i,f,g,o
    const int grow  = gate2 * NH + j0 + (ln & 7);    // row in w_ih/w_hh
#pragma unroll
    for (int s = 0; s < 16; ++s)
      split8s(w_hh + (size_t)grow * NH + 32 * s + 8 * (lane >> 4), whh_hi[s], whh_lo[s]);
#pragma unroll
    for (int s = 0; s < 8; ++s)
      split8s(w_ih + (size_t)grow * NI + 32 * s + 8 * (lane >> 4), wih_hi[s], wih_lo[s]);
  }

  // ---- per-thread pointwise assignment: one (batch, hidden-col) cell ----
  const int b_l = tid >> 3;        // 0..15
  const int jj  = tid & 7;         // 0..7
  const int bg  = b0 + b_l;
  const int jg  = j0 + jj;

  float c_s = c0[bg * NH + jg];
  const float bias_i = b_ih[jg]          + b_hh[jg];
  const float bias_f = b_ih[NH + jg]     + b_hh[NH + jg];
  const float bias_g = b_ih[2 * NH + jg] + b_hh[2 * NH + jg];
  const float bias_o = b_ih[3 * NH + jg] + b_hh[3 * NH + jg];

  const int PAR = NB * NH;   // parity stride (u32 cells)

  // ---- publish packed h0 into hbuf parity 0 ----
  __hip_atomic_store(&hbuf[bg * NH + jg], pack_cell(h0[bg * NH + jg]),
                     __ATOMIC_RELAXED, __HIP_MEMORY_SCOPE_AGENT);
  __builtin_amdgcn_fence(__ATOMIC_RELEASE, "agent");
  __syncthreads();
  if (tid == 0)
    __hip_atomic_store(&flags[mh * 64 + ng], 1, __ATOMIC_RELEASE, __HIP_MEMORY_SCOPE_AGENT);

  const int arow = b0 + ln;        // A-fragment batch row (id matches probe rowv)
  const int lq   = lane >> 4;
  const int fidx = mh * 64 + lane; // this lane's flag to poll (group-local)

  for (int t = 0; t < NTS; ++t) {
    // prefetch + split x fragments (read-only; overlaps the barrier poll)
    half8 axh[8], axl[8];
#pragma unroll
    for (int s = 0; s < 8; ++s)
      split8s(x + ((size_t)t * NB + arow) * NI + 32 * s + 8 * lq, axh[s], axl[s]);

    // ---- group barrier: all 64 wgs of this batch group published h_t ----
    {
      const int target = t + 1;
      if (tid < 64) {
        while (__hip_atomic_load(&flags[fidx], __ATOMIC_ACQUIRE, __HIP_MEMORY_SCOPE_AGENT) < target)
          __builtin_amdgcn_s_sleep(1);
      }
      __syncthreads();
      __builtin_amdgcn_fence(__ATOMIC_ACQUIRE, "agent");
    }

    // ---- gates = h_t*Whh^T + x_t*Wih^T, scaled-split f16, fp32 accum ----
    floatx4 acc  = {0.f, 0.f, 0.f, 0.f};   // hi*hi products
    floatx4 accl = {0.f, 0.f, 0.f, 0.f};   // cross products (carry 2^12 scale)
    const unsigned* hb = hbuf + (t & 1) * PAR;
#pragma unroll
    for (int s = 0; s < 16; ++s) {
      half8 ah, al;
      load_cells(hb + arow * NH + 32 * s + 8 * lq, ah, al);
      acc  = __builtin_amdgcn_mfma_f32_16x16x32_f16(ah, whh_hi[s], acc,  0, 0, 0);
      accl = __builtin_amdgcn_mfma_f32_16x16x32_f16(al, whh_hi[s], accl, 0, 0, 0);
      accl = __builtin_amdgcn_mfma_f32_16x16x32_f16(ah, whh_lo[s], accl, 0, 0, 0);
    }
#pragma unroll
    for (int s = 0; s < 8; ++s) {
      acc  = __builtin_amdgcn_mfma_f32_16x16x32_f16(axh[s], wih_hi[s], acc,  0, 0, 0);
      accl = __builtin_amdgcn_mfma_f32_16x16x32_f16(axl[s], wih_hi[s], accl, 0, 0, 0);
      accl = __builtin_amdgcn_mfma_f32_16x16x32_f16(axh[s], wih_lo[s], accl, 0, 0, 0);
    }

    // ---- scatter to LDS using the EMPIRICALLY decoded slot coordinates ----
#pragma unroll
    for (int r = 0; r < 4; ++r)
      gates[row_l[r]][wv * 16 + col_l[r]] = acc[r] + accl[r] * LOINV;
    __syncthreads();

    // ---- pointwise LSTM cell (fp32) ----
    float xi = gates[b_l][jj]      + bias_i;
    float xf = gates[b_l][8 + jj]  + bias_f;
    float xg = gates[b_l][16 + jj] + bias_g;
    float xo = gates[b_l][24 + jj] + bias_o;
    float ig = 1.f / (1.f + __expf(-xi));
    float fg = 1.f / (1.f + __expf(-xf));
    float gg = 2.f / (1.f + __expf(-2.f * xg)) - 1.f;   // tanh
    float og = 1.f / (1.f + __expf(-xo));
    c_s = fg * c_s + ig * gg;
    float tc = 2.f / (1.f + __expf(-2.f * c_s)) - 1.f;  // tanh(c)
    float hn = og * tc;

    out[((size_t)t * NB + bg) * NH + jg] = hn;          // FP32 store

    // publish packed h_{t+1} (agent-scope atomic store: reaches coherence point)
    __hip_atomic_store(&hbuf[((t + 1) & 1) * PAR + bg * NH + jg], pack_cell(hn),
                       __ATOMIC_RELAXED, __HIP_MEMORY_SCOPE_AGENT);

    if (t < NTS - 1) {
      __builtin_amdgcn_fence(__ATOMIC_RELEASE, "agent");
      __syncthreads();
      if (tid == 0)
        __hip_atomic_store(&flags[mh * 64 + ng], t + 2, __ATOMIC_RELEASE, __HIP_MEMORY_SCOPE_AGENT);
    } else {
      const size_t hf_off = (size_t)NTS * NB * NH;
      out[hf_off + bg * NH + jg] = hn;                          // h_f FP32
      out[hf_off + (size_t)NB * NH + bg * NH + jg] = c_s;       // c_f FP32
    }
  }
}

extern "C" void kernel_launch(void* const* d_in, const int* in_sizes, int n_in,
                              void* d_out, int out_size, void* d_ws, size_t ws_size,
                              hipStream_t stream) {
  const float* x    = (const float*)d_in[0];
  const float* h0   = (const float*)d_in[1];
  const float* c0   = (const float*)d_in[2];
  const float* w_ih = (const float*)d_in[3];
  const float* w_hh = (const float*)d_in[4];
  const float* b_ih = (const float*)d_in[5];
  const float* b_hh = (const float*)d_in[6];
  float* out = (float*)d_out;
  unsigned* hbuf = (unsigned*)d_ws;                    // 2*64*512 u32 = 256 KB
  int* flags = (int*)((char*)d_ws + (size_t)2 * NB * NH * sizeof(unsigned));

  // ws is poisoned 0xAA before every timed launch: flags must be re-zeroed.
  hipMemsetAsync(flags, 0, NWG * sizeof(int), stream);
  hipLaunchKernelGGL(lstm_persist_v6, dim3(NWG), dim3(NTHR), 0, stream,
                     x, h0, c0, w_ih, w_hh, b_ih, b_hh, out, hbuf, flags);
}

// Round 7
// 6980.712 us; speedup vs baseline: 2.0089x; 2.0089x over previous
//
#include <hip/hip_runtime.h>
#include <hip/hip_bf16.h>

typedef __attribute__((ext_vector_type(8))) _Float16 half8;
typedef __attribute__((ext_vector_type(4))) float floatx4;

#define NTS 512    // timesteps
#define NB  64     // batch
#define NI  256    // input dim
#define NH  512    // hidden
#define NWG 256
#define NTHR 128

#define LOSCALE 4096.0f
#define LOINV   (1.0f / 4096.0f)

// fp32 -> (hi f16, lo f16 scaled by 2^12)
static __device__ __forceinline__ void split8s(const float* p, half8& hi, half8& lo) {
  float4 a = *(const float4*)p;
  float4 b = *(const float4*)(p + 4);
  float v[8] = {a.x, a.y, a.z, a.w, b.x, b.y, b.z, b.w};
#pragma unroll
  for (int i = 0; i < 8; ++i) {
    _Float16 h = (_Float16)v[i];
    hi[i] = h;
    lo[i] = (_Float16)((v[i] - (float)h) * LOSCALE);
  }
}

// pack one h cell: low16 = hi(f16), high16 = lo(f16, scaled 2^12)
static __device__ __forceinline__ unsigned pack_cell(float v) {
  _Float16 h = (_Float16)v;
  _Float16 l = (_Float16)((v - (float)h) * LOSCALE);
  union { _Float16 f; unsigned short s; } uh, ul;
  uh.f = h; ul.f = l;
  return ((unsigned)ul.s << 16) | (unsigned)uh.s;
}

// 8 packed cells via 4 agent-scope u64 atomic loads (coherent by construction)
static __device__ __forceinline__ void load_cells(const unsigned* p, half8& ah, half8& al) {
  union { unsigned u[4]; half8 h; } A, L;
#pragma unroll
  for (int q = 0; q < 4; ++q) {
    unsigned long long Q = __hip_atomic_load((const unsigned long long*)(p + 2 * q),
                                             __ATOMIC_RELAXED, __HIP_MEMORY_SCOPE_AGENT);
    unsigned c0 = (unsigned)Q, c1 = (unsigned)(Q >> 32);
    A.u[q] = (c0 & 0xFFFFu) | (c1 << 16);
    L.u[q] = (c0 >> 16)     | (c1 & 0xFFFF0000u);
  }
  ah = A.h; al = L.h;
}

// Persistent LSTM, fp32 out. NO per-step cache fences: all cross-wg data moves via
// agent-scope atomics (per-access coherence bits); ordering via s_waitcnt + flags.
// Weight hi-planes in VGPRs, lo-planes in LDS (keeps VGPR pressure under control
// so the compiler doesn't re-load weights from global every step).
__global__ void __launch_bounds__(NTHR, 1) lstm_persist_v7(
    const float* __restrict__ x,     // [512][64][256] fp32
    const float* __restrict__ h0,    // [64][512] fp32
    const float* __restrict__ c0,    // [64][512] fp32
    const float* __restrict__ w_ih,  // [2048][256] fp32
    const float* __restrict__ w_hh,  // [2048][512] fp32
    const float* __restrict__ b_ih,  // [2048] fp32
    const float* __restrict__ b_hh,  // [2048] fp32
    float* __restrict__ out,         // [512][64][512] ++ h_f ++ c_f (fp32)
    unsigned* __restrict__ hbuf,     // [2][64][512] packed u32 cells
    int* __restrict__ flags)         // [256] = [mh][ng], pre-zeroed
{
  const int wg   = blockIdx.x;
  const int mh   = wg & 3;        // batch quarter (group)
  const int ng   = wg >> 2;       // hidden-col group (8 cols)
  const int b0   = mh * 16;
  const int j0   = ng * 8;
  const int tid  = threadIdx.x;
  const int wv   = tid >> 6;      // 0: gates i,f   1: gates g,o
  const int lane = tid & 63;
  const int ln   = lane & 15;
  const int lq   = lane >> 4;

  __shared__ float gates[16][33];        // gate tile for the pointwise stage
  __shared__ uint4 wlo[2][24][64];       // weight LO planes: [wave][ktile][lane], 48 KB

  // ---- EMPIRICAL layout probes: decode (local_row, local_col) of each acc slot ----
  int row_l[4], col_l[4];
  {
    half8 ones, rowv;
#pragma unroll
    for (int i = 0; i < 8; ++i) { ones[i] = (_Float16)1.0f; rowv[i] = (_Float16)(float)ln; }
    floatx4 z = {0.f, 0.f, 0.f, 0.f};
    floatx4 p1 = __builtin_amdgcn_mfma_f32_16x16x32_f16(rowv, ones, z, 0, 0, 0);
    floatx4 p2 = __builtin_amdgcn_mfma_f32_16x16x32_f16(ones, rowv, z, 0, 0, 0);
#pragma unroll
    for (int r = 0; r < 4; ++r) {
      row_l[r] = (int)(p1[r] * (1.0f / 32.0f) + 0.5f);
      col_l[r] = (int)(p2[r] * (1.0f / 32.0f) + 0.5f);
    }
  }

  // ---- weights: hi-planes -> VGPR arrays; lo-planes -> LDS ----
  half8 whh_hi[16], wih_hi[8];
  {
    const int gate2 = wv * 2 + (ln >> 3);            // 0..3 = i,f,g,o
    const int grow  = gate2 * NH + j0 + (ln & 7);    // row in w_ih/w_hh
#pragma unroll
    for (int s = 0; s < 16; ++s) {
      half8 lo;
      split8s(w_hh + (size_t)grow * NH + 32 * s + 8 * lq, whh_hi[s], lo);
      union { half8 h; uint4 u; } cv; cv.h = lo;
      wlo[wv][s][lane] = cv.u;
    }
#pragma unroll
    for (int s = 0; s < 8; ++s) {
      half8 lo;
      split8s(w_ih + (size_t)grow * NI + 32 * s + 8 * lq, wih_hi[s], lo);
      union { half8 h; uint4 u; } cv; cv.h = lo;
      wlo[wv][16 + s][lane] = cv.u;
    }
  }

  // ---- per-thread pointwise assignment: one (batch, hidden-col) cell ----
  const int b_l = tid >> 3;        // 0..15
  const int jj  = tid & 7;         // 0..7
  const int bg  = b0 + b_l;
  const int jg  = j0 + jj;

  float c_s = c0[bg * NH + jg];
  const float bias_i = b_ih[jg]          + b_hh[jg];
  const float bias_f = b_ih[NH + jg]     + b_hh[NH + jg];
  const float bias_g = b_ih[2 * NH + jg] + b_hh[2 * NH + jg];
  const float bias_o = b_ih[3 * NH + jg] + b_hh[3 * NH + jg];

  const int PAR = NB * NH;   // parity stride (u32 cells)

  // ---- publish packed h0 into hbuf parity 0 ----
  __hip_atomic_store(&hbuf[bg * NH + jg], pack_cell(h0[bg * NH + jg]),
                     __ATOMIC_RELAXED, __HIP_MEMORY_SCOPE_AGENT);
  __builtin_amdgcn_s_waitcnt(0);               // drain own store to coherence point
  asm volatile("" ::: "memory");
  __syncthreads();                              // all threads drained + LDS weights ready
  if (tid == 0)
    __hip_atomic_store(&flags[mh * 64 + ng], 1, __ATOMIC_RELAXED, __HIP_MEMORY_SCOPE_AGENT);

  const int arow = b0 + ln;        // A-fragment batch row
  const int fidx = mh * 64 + lane; // this lane's flag to poll (group-local)

  for (int t = 0; t < NTS; ++t) {
    // prefetch + split x fragments (plain cached loads; overlaps the barrier poll)
    half8 axh[8], axl[8];
#pragma unroll
    for (int s = 0; s < 8; ++s)
      split8s(x + ((size_t)t * NB + arow) * NI + 32 * s + 8 * lq, axh[s], axl[s]);

    // ---- group barrier: all 64 wgs of this batch group published h_t ----
    {
      const int target = t + 1;
      if (tid < 64) {
        while (__hip_atomic_load(&flags[fidx], __ATOMIC_RELAXED, __HIP_MEMORY_SCOPE_AGENT) < target)
          __builtin_amdgcn_s_sleep(1);
      }
      __syncthreads();
      asm volatile("" ::: "memory");
    }

    // ---- gates = h_t*Whh^T + x_t*Wih^T, scaled-split f16, fp32 accum ----
    floatx4 acc  = {0.f, 0.f, 0.f, 0.f};   // hi*hi products
    floatx4 accl = {0.f, 0.f, 0.f, 0.f};   // cross products (carry 2^12 scale)
    const unsigned* hb = hbuf + (t & 1) * PAR;
#pragma unroll
    for (int s = 0; s < 16; ++s) {
      half8 ah, al;
      load_cells(hb + arow * NH + 32 * s + 8 * lq, ah, al);
      union { uint4 u; half8 h; } wl; wl.u = wlo[wv][s][lane];
      acc  = __builtin_amdgcn_mfma_f32_16x16x32_f16(ah, whh_hi[s], acc,  0, 0, 0);
      accl = __builtin_amdgcn_mfma_f32_16x16x32_f16(al, whh_hi[s], accl, 0, 0, 0);
      accl = __builtin_amdgcn_mfma_f32_16x16x32_f16(ah, wl.h,      accl, 0, 0, 0);
    }
#pragma unroll
    for (int s = 0; s < 8; ++s) {
      union { uint4 u; half8 h; } wl; wl.u = wlo[wv][16 + s][lane];
      acc  = __builtin_amdgcn_mfma_f32_16x16x32_f16(axh[s], wih_hi[s], acc,  0, 0, 0);
      accl = __builtin_amdgcn_mfma_f32_16x16x32_f16(axl[s], wih_hi[s], accl, 0, 0, 0);
      accl = __builtin_amdgcn_mfma_f32_16x16x32_f16(axh[s], wl.h,      accl, 0, 0, 0);
    }

    // ---- scatter to LDS using the empirically decoded slot coordinates ----
#pragma unroll
    for (int r = 0; r < 4; ++r)
      gates[row_l[r]][wv * 16 + col_l[r]] = acc[r] + accl[r] * LOINV;
    __syncthreads();

    // ---- pointwise LSTM cell (fp32) ----
    float xi = gates[b_l][jj]      + bias_i;
    float xf = gates[b_l][8 + jj]  + bias_f;
    float xg = gates[b_l][16 + jj] + bias_g;
    float xo = gates[b_l][24 + jj] + bias_o;
    float ig = 1.f / (1.f + __expf(-xi));
    float fg = 1.f / (1.f + __expf(-xf));
    float gg = 2.f / (1.f + __expf(-2.f * xg)) - 1.f;   // tanh
    float og = 1.f / (1.f + __expf(-xo));
    c_s = fg * c_s + ig * gg;
    float tc = 2.f / (1.f + __expf(-2.f * c_s)) - 1.f;  // tanh(c)
    float hn = og * tc;

    // publish packed h_{t+1} FIRST (critical path), then raise flag, then out store
    __hip_atomic_store(&hbuf[((t + 1) & 1) * PAR + bg * NH + jg], pack_cell(hn),
                       __ATOMIC_RELAXED, __HIP_MEMORY_SCOPE_AGENT);

    if (t < NTS - 1) {
      __builtin_amdgcn_s_waitcnt(0);           // own h store globally visible
      asm volatile("" ::: "memory");
      __syncthreads();                          // whole wg drained
      if (tid == 0)
        __hip_atomic_store(&flags[mh * 64 + ng], t + 2, __ATOMIC_RELAXED, __HIP_MEMORY_SCOPE_AGENT);
      out[((size_t)t * NB + bg) * NH + jg] = hn;   // off the critical path
    } else {
      out[((size_t)t * NB + bg) * NH + jg] = hn;
      const size_t hf_off = (size_t)NTS * NB * NH;
      out[hf_off + bg * NH + jg] = hn;                          // h_f
      out[hf_off + (size_t)NB * NH + bg * NH + jg] = c_s;       // c_f
    }
  }
}

extern "C" void kernel_launch(void* const* d_in, const int* in_sizes, int n_in,
                              void* d_out, int out_size, void* d_ws, size_t ws_size,
                              hipStream_t stream) {
  const float* x    = (const float*)d_in[0];
  const float* h0   = (const float*)d_in[1];
  const float* c0   = (const float*)d_in[2];
  const float* w_ih = (const float*)d_in[3];
  const float* w_hh = (const float*)d_in[4];
  const float* b_ih = (const float*)d_in[5];
  const float* b_hh = (const float*)d_in[6];
  float* out = (float*)d_out;
  unsigned* hbuf = (unsigned*)d_ws;                    // 2*64*512 u32 = 256 KB
  int* flags = (int*)((char*)d_ws + (size_t)2 * NB * NH * sizeof(unsigned));

  // ws is poisoned 0xAA before every timed launch: flags must be re-zeroed.
  hipMemsetAsync(flags, 0, NWG * sizeof(int), stream);
  hipLaunchKernelGGL(lstm_persist_v7, dim3(NWG), dim3(NTHR), 0, stream,
                     x, h0, c0, w_ih, w_hh, b_ih, b_hh, out, hbuf, flags);
}